// Round 6
// baseline (239.060 us; speedup 1.0000x reference)
//
#include <hip/hip_runtime.h>

// IF (integrate-and-fire) SNN forward scan.
// x: [T*B, C, H, W] fp32 viewed as [T=8, slice=4,194,304 floats]; out same shape.
// Per element n: mem=0.5*thr; for t: mem+=x[t][n]; sp=(mem>=thr)?thr:0; mem-=sp.
//
// R1-R5 all landed 75-100 us (~3.5 TB/s eff) regardless of structure.
// ROOT CAUSE FOUND R6: VGPR_Count=32 in EVERY round. 8 in-flight float4 loads
// need 32 VGPRs for data alone -> compiler was recycling load dest registers
// and inserting s_waitcnt BETWEEN loads, serializing MLP to ~2-3 deep. All
// structural experiments compiled to the same register-starved loop.
// R6: __launch_bounds__(256, 4) -> 128-VGPR budget, 4 waves/SIMD. Keep R5's
// pipelined persistent structure (GRID=1024 -> 4 iters/thread) + nt loads
// + nt stores (R3/R4 established nt loads are a big win here).
// Verification bit: VGPR_Count must jump to ~96-128, else attribute didn't take.

typedef float f4 __attribute__((ext_vector_type(4)));

constexpr int T_STEPS = 8;
constexpr int BLOCK   = 256;
constexpr int GRID    = 1024;   // 262,144 threads -> exactly 4 iters/thread

__global__ __launch_bounds__(BLOCK, 4) void if_fwd_kernel(
    const f4* __restrict__ x,
    const float* __restrict__ thresh,
    f4* __restrict__ out,
    int stride4)   // float4s per timestep slice (1,048,576)
{
    const int nthreads = GRID * BLOCK;
    const int tid      = blockIdx.x * BLOCK + threadIdx.x;
    const float thr    = thresh[0];      // wave-uniform -> scalar load
    const float h      = 0.5f * thr;
    const int iters    = stride4 / nthreads;   // 4 (exact division)

    int i = tid;

    // Prologue: 8 independent 16B nt loads, distinct dest regs (now affordable).
    f4 cur[T_STEPS];
#pragma unroll
    for (int t = 0; t < T_STEPS; ++t) {
        cur[t] = __builtin_nontemporal_load(x + (size_t)t * stride4 + i);
    }

    // Steady state: prefetch tile n+1 BEFORE storing tile n (next load-wait
    // must not sit behind this iteration's store acks in the in-order vmcnt).
    for (int n = 0; n < iters - 1; ++n) {
        const int inext = i + nthreads;
        f4 nxt[T_STEPS];
#pragma unroll
        for (int t = 0; t < T_STEPS; ++t) {
            nxt[t] = __builtin_nontemporal_load(x + (size_t)t * stride4 + inext);
        }

        f4 m = {h, h, h, h};
#pragma unroll
        for (int t = 0; t < T_STEPS; ++t) {
            m += cur[t];
            f4 s;
#pragma unroll
            for (int k = 0; k < 4; ++k) {
                s[k] = (m[k] >= thr) ? thr : 0.0f;
            }
            m -= s;
            __builtin_nontemporal_store(s, out + (size_t)t * stride4 + i);
        }

#pragma unroll
        for (int t = 0; t < T_STEPS; ++t) {
            cur[t] = nxt[t];
        }
        i = inext;
    }

    // Epilogue: last tile.
    {
        f4 m = {h, h, h, h};
#pragma unroll
        for (int t = 0; t < T_STEPS; ++t) {
            m += cur[t];
            f4 s;
#pragma unroll
            for (int k = 0; k < 4; ++k) {
                s[k] = (m[k] >= thr) ? thr : 0.0f;
            }
            m -= s;
            __builtin_nontemporal_store(s, out + (size_t)t * stride4 + i);
        }
    }
}

extern "C" void kernel_launch(void* const* d_in, const int* in_sizes, int n_in,
                              void* d_out, int out_size, void* d_ws, size_t ws_size,
                              hipStream_t stream) {
    const float* x      = (const float*)d_in[0];   // [T*B, C, H, W] fp32
    const float* thresh = (const float*)d_in[1];   // scalar threshold (1 elem)
    float* out          = (float*)d_out;

    const int total   = in_sizes[0];       // 33,554,432
    const int stride  = total / T_STEPS;   // 4,194,304 elems per slice
    const int stride4 = stride / 4;        // 1,048,576 float4s per slice

    if_fwd_kernel<<<dim3(GRID), dim3(BLOCK), 0, stream>>>(
        (const f4*)x, thresh, (f4*)out, stride4);
}

// Round 7
// 232.499 us; speedup vs baseline: 1.0282x; 1.0282x over previous
//
#include <hip/hip_runtime.h>

// IF (integrate-and-fire) SNN forward scan.
// x: [T*B, C, H, W] fp32 viewed as [T=8, slice=4,194,304 floats]; out same shape.
// Per element n: mem=0.5*thr; for t: mem+=x[t][n]; sp=(mem>=thr)?thr:0; mem-=sp.
//
// R1: one-shot float4, normal ld/st       -> 90 us  (VGPR 28)
// R2: one-shot ILP=2 + nt stores          -> 83 us  (VGPR 32)
// R3: persistent + nt ld + nt st          -> <80 us (invisible in top-5)
// R4: R3 w/ normal loads                  -> 100 us (VGPR 32, FETCH identical ->
//     nt-load win is not traffic; likely L1/miss-queue path)
// R5: + SW pipeline                       -> ~R3 (VGPR still 32! pipeline flattened)
// R6: + launch_bounds(256,4)              -> unobservable (kernel left top-5)
//
// THEORY (quantified): fill kernel does 6.7 TB/s at 9% occ / 8 VGPR because
// stores need no waits (unbounded per-wave MLP). Our loads DO need waits;
// at VGPR=32 the compiler recycles load dests -> ~2 loads in flight/wave ->
// observed 2.5 TB/s. Need ~5 wave-loads outstanding per CU total to saturate.
// R7: FORCE 8-deep load MLP: launch_bounds(256,4) (128-VGPR cap) +
// sched_barrier(0) after the prefetch loop (loads cannot be sunk past it ->
// compiler must allocate 8 distinct float4 dests). One-shot grid so the
// kernel is visible in rocprof either way. nt loads + nt stores (best known).

typedef float f4 __attribute__((ext_vector_type(4)));

constexpr int T_STEPS = 8;
constexpr int BLOCK   = 256;

__global__ __launch_bounds__(BLOCK, 4) void if_fwd_kernel(
    const f4* __restrict__ x,
    const float* __restrict__ thresh,
    f4* __restrict__ out,
    int stride4)   // float4s per timestep slice (1,048,576)
{
    const int i = blockIdx.x * BLOCK + threadIdx.x;
    if (i >= stride4) return;

    const float thr = thresh[0];      // wave-uniform -> scalar load
    const float h   = 0.5f * thr;

    // 8 independent 16B nt loads. sched_barrier(0) below forbids sinking any
    // load past it -> all 8 must be issued, with distinct dest VGPRs, before
    // any consumption. This is the whole experiment.
    f4 xt[T_STEPS];
#pragma unroll
    for (int t = 0; t < T_STEPS; ++t) {
        xt[t] = __builtin_nontemporal_load(x + (size_t)t * stride4 + i);
    }
    __builtin_amdgcn_sched_barrier(0);

    f4 m = {h, h, h, h};
#pragma unroll
    for (int t = 0; t < T_STEPS; ++t) {
        m += xt[t];
        f4 s;
#pragma unroll
        for (int k = 0; k < 4; ++k) {
            s[k] = (m[k] >= thr) ? thr : 0.0f;
        }
        m -= s;
        __builtin_nontemporal_store(s, out + (size_t)t * stride4 + i);
    }
}

extern "C" void kernel_launch(void* const* d_in, const int* in_sizes, int n_in,
                              void* d_out, int out_size, void* d_ws, size_t ws_size,
                              hipStream_t stream) {
    const float* x      = (const float*)d_in[0];   // [T*B, C, H, W] fp32
    const float* thresh = (const float*)d_in[1];   // scalar threshold (1 elem)
    float* out          = (float*)d_out;

    const int total   = in_sizes[0];       // 33,554,432
    const int stride  = total / T_STEPS;   // 4,194,304 elems per slice
    const int stride4 = stride / 4;        // 1,048,576 float4s per slice

    dim3 block(BLOCK);
    dim3 grid((stride4 + BLOCK - 1) / BLOCK);   // 4096 blocks, one-shot
    if_fwd_kernel<<<grid, block, 0, stream>>>(
        (const f4*)x, thresh, (f4*)out, stride4);
}